// Round 1
// baseline (306.840 us; speedup 1.0000x reference)
//
#include <hip/hip_runtime.h>

// Problem dims (from reference setup_inputs): T=256, B=128, I=512, H=512
#define T_STEPS 256
#define B_DIM   128
#define I_DIM   512
#define H_DIM   512
#define M_DIM   (T_STEPS * B_DIM)   // 32768 rows of the flattened GEMM

// GEMM tiling
#define BM 128
#define BN 128
#define BK 32
#define LDA (BM + 4)   // +4 floats pad keeps 16B alignment for b128 reads
#define LDB (BN + 4)

// h[m][n] = sum_k x[m][k] * W[n][k] + b[n]
// A (x) is [M][K] row-major, Bw (W) is [N][K] row-major -> both K-major.
__global__ __launch_bounds__(256, 2) void gemm_bias_f32(
    const float* __restrict__ A,
    const float* __restrict__ Bw,
    const float* __restrict__ bias,
    float* __restrict__ C)
{
    __shared__ float As[BK][LDA];   // transposed: As[k][m]
    __shared__ float Bs[BK][LDB];   // transposed: Bs[k][n]

    const int tid = threadIdx.x;
    const int tx  = tid & 15;   // n direction (16 threads)
    const int ty  = tid >> 4;   // m direction (16 threads)
    const int m0  = blockIdx.y * BM;
    const int n0  = blockIdx.x * BN;

    float acc[8][8];
    #pragma unroll
    for (int i = 0; i < 8; i++)
        #pragma unroll
        for (int j = 0; j < 8; j++)
            acc[i][j] = 0.0f;

    // Tile-staging mapping: each thread loads 4x float4 from A and Bw.
    const int lrow = tid >> 3;        // 0..31 (row within 32-row slab)
    const int lk   = (tid & 7) * 4;   // k offset 0,4,...,28

    const float* Aptr = A  + (size_t)(m0 + lrow) * I_DIM + lk;
    const float* Bptr = Bw + (size_t)(n0 + lrow) * I_DIM + lk;

    for (int k0 = 0; k0 < I_DIM; k0 += BK) {
        float4 av[4], bv[4];
        #pragma unroll
        for (int p = 0; p < 4; p++) {
            av[p] = *(const float4*)(Aptr + (size_t)(p * 32) * I_DIM + k0);
            bv[p] = *(const float4*)(Bptr + (size_t)(p * 32) * I_DIM + k0);
        }

        __syncthreads();   // protect prior iteration's LDS reads

        #pragma unroll
        for (int p = 0; p < 4; p++) {
            const int r = lrow + p * 32;
            As[lk + 0][r] = av[p].x;
            As[lk + 1][r] = av[p].y;
            As[lk + 2][r] = av[p].z;
            As[lk + 3][r] = av[p].w;
            Bs[lk + 0][r] = bv[p].x;
            Bs[lk + 1][r] = bv[p].y;
            Bs[lk + 2][r] = bv[p].z;
            Bs[lk + 3][r] = bv[p].w;
        }

        __syncthreads();

        for (int k = 0; k < BK; k++) {
            float4 a0 = *(const float4*)&As[k][ty * 8];
            float4 a1 = *(const float4*)&As[k][ty * 8 + 4];
            float4 b0 = *(const float4*)&Bs[k][tx * 8];
            float4 b1 = *(const float4*)&Bs[k][tx * 8 + 4];
            float a[8] = {a0.x, a0.y, a0.z, a0.w, a1.x, a1.y, a1.z, a1.w};
            float b[8] = {b0.x, b0.y, b0.z, b0.w, b1.x, b1.y, b1.z, b1.w};
            #pragma unroll
            for (int i = 0; i < 8; i++)
                #pragma unroll
                for (int j = 0; j < 8; j++)
                    acc[i][j] = fmaf(a[i], b[j], acc[i][j]);
        }
    }

    // Epilogue: add bias, write float4s
    float bcol[8];
    #pragma unroll
    for (int j = 0; j < 8; j++)
        bcol[j] = bias[n0 + tx * 8 + j];

    #pragma unroll
    for (int i = 0; i < 8; i++) {
        const int m = m0 + ty * 8 + i;
        float4 o0, o1;
        o0.x = acc[i][0] + bcol[0];
        o0.y = acc[i][1] + bcol[1];
        o0.z = acc[i][2] + bcol[2];
        o0.w = acc[i][3] + bcol[3];
        o1.x = acc[i][4] + bcol[4];
        o1.y = acc[i][5] + bcol[5];
        o1.z = acc[i][6] + bcol[6];
        o1.w = acc[i][7] + bcol[7];
        float* cp = C + (size_t)m * H_DIM + n0 + tx * 8;
        *(float4*)(cp)     = o0;
        *(float4*)(cp + 4) = o1;
    }
}

// LIF scan over T. One thread per neuron (b, j); n = B*H neurons.
// v <- v/2 + h_t ; s = (v >= 1) ; v <- s ? 0 : v
#define SCAN_UNROLL 16
__global__ __launch_bounds__(256) void lif_scan(
    const float* __restrict__ h,
    float* __restrict__ out)
{
    const int n   = B_DIM * H_DIM;   // 65536
    const int idx = blockIdx.x * 256 + threadIdx.x;
    const float* hp = h + idx;
    float* op = out + idx;

    float v = 0.0f;
    for (int t0 = 0; t0 < T_STEPS; t0 += SCAN_UNROLL) {
        float hv[SCAN_UNROLL];
        #pragma unroll
        for (int i = 0; i < SCAN_UNROLL; i++)
            hv[i] = hp[(size_t)(t0 + i) * n];

        float s[SCAN_UNROLL];
        #pragma unroll
        for (int i = 0; i < SCAN_UNROLL; i++) {
            v = 0.5f * v + hv[i];
            const bool fire = (v >= 1.0f);
            s[i] = fire ? 1.0f : 0.0f;
            v    = fire ? 0.0f : v;
        }

        #pragma unroll
        for (int i = 0; i < SCAN_UNROLL; i++)
            op[(size_t)(t0 + i) * n] = s[i];
    }
}

extern "C" void kernel_launch(void* const* d_in, const int* in_sizes, int n_in,
                              void* d_out, int out_size, void* d_ws, size_t ws_size,
                              hipStream_t stream) {
    const float* x = (const float*)d_in[0];   // (T, B, I) fp32
    const float* W = (const float*)d_in[1];   // (H, I)    fp32
    const float* b = (const float*)d_in[2];   // (H,)      fp32
    float* out = (float*)d_out;               // (T, B, H) fp32 spikes
    float* h   = (float*)d_ws;                // (T*B, H) fp32 scratch = 64 MB

    dim3 grid(H_DIM / BN, M_DIM / BM);        // (4, 256)
    gemm_bias_f32<<<grid, 256, 0, stream>>>(x, W, b, h);

    lif_scan<<<(B_DIM * H_DIM) / 256, 256, 0, stream>>>(h, out);
}